// Round 2
// baseline (427.241 us; speedup 1.0000x reference)
//
#include <hip/hip_runtime.h>
#include <math.h>

#define N      128
#define NSQ    (N * N)          // 16384
#define VOL    (N * N * N)      // 2097152
#define NSHELL 64
#define BTOT   8
#define FPI    3.14159265358979323846f

#define TPX    17               // k2 tile pitch in floats (odd -> conflict-free column pulls)

// ---------------------------------------------------------------------------
// Per-lane twiddles for the wave-register 128-pt DIF FFT (verified round 1).
// tc/ts[0]: w = exp(-i*pi*l/64) for the in-lane h=64 stage.
// k=1..6 (h=32..1): lo lanes ((l&h)==0) get (1,0); hi lanes get
// exp(-i*pi*(l&(h-1))/h). Sign e = (l&h)? -1 : +1 recomputed per stage.
// ---------------------------------------------------------------------------
__device__ inline void mk_tw(int l, float* tc, float* ts) {
    __sincosf(-FPI * (float)l * (1.0f / 64.0f), &ts[0], &tc[0]);
#pragma unroll
    for (int k = 1; k <= 6; ++k) {
        const int h = 64 >> k;
        float s, c;
        __sincosf(-FPI * (float)(l & (h - 1)) / (float)h, &s, &c);
        const bool hi = (l & h) != 0;
        tc[k] = hi ? c : 1.0f;
        ts[k] = hi ? s : 0.0f;
    }
}

// ---------------------------------------------------------------------------
// 128-point DIF (Gentleman-Sande) FFT across one 64-lane wave.
// In:  lane l holds a[l] (v0), a[l+64] (v1), natural order.
// Out: lane l holds bins 2*bitrev6(l) (v0) and 2*bitrev6(l)+1 (v1).
// ---------------------------------------------------------------------------
__device__ inline void fft128(float2& v0, float2& v1,
                              const float* tc, const float* ts, int l) {
    {   // h = 64: in-lane, twiddle m = l
        const float dx = v0.x - v1.x, dy = v0.y - v1.y;
        v0.x += v1.x; v0.y += v1.y;
        v1.x = dx * tc[0] - dy * ts[0];
        v1.y = dx * ts[0] + dy * tc[0];
    }
#pragma unroll
    for (int k = 1; k <= 6; ++k) {
        const int h = 64 >> k;           // 32,16,8,4,2,1
        const float e = (l & h) ? -1.0f : 1.0f;
        const float c = tc[k], s = ts[k];
        const float o0x = __shfl_xor(v0.x, h), o0y = __shfl_xor(v0.y, h);
        const float o1x = __shfl_xor(v1.x, h), o1y = __shfl_xor(v1.y, h);
        const float t0x = fmaf(e, v0.x, o0x), t0y = fmaf(e, v0.y, o0y);
        const float t1x = fmaf(e, v1.x, o1x), t1y = fmaf(e, v1.y, o1y);
        v0.x = t0x * c - t0y * s;  v0.y = t0x * s + t0y * c;
        v1.x = t1x * c - t1y * s;  v1.y = t1x * s + t1y * c;
    }
}

// slot <-> bin permutation (involution): bin(slot s) = 2*bitrev6(s>>1) + (s&1)
__device__ inline int binof(int s) {
    return (int)(((__brev((unsigned)(s >> 1)) >> 26) << 1) | (unsigned)(s & 1));
}

// ---------------------------------------------------------------------------
// Pass 1 (fused z+y FFT): one block per (batch, x).
// LDS = 4 XOR-swizzled planes p{0,1}{re,im}[64][128] = exactly 128 KiB.
// Plane r row j holds z-slot 2j+r (bin beta(2j+r)), columns = spatial y,
// element (j, y) stored at j*128 + (y ^ (j&31)):
//   phase-1 store (row = lane l, col = y uniform): banks y^(l&31) -> free
//   phase-2 read  (row = j uniform, col = lane l): banks l^(j&31) -> free
// Phase 2 y-FFTs each z-slot column and stores straight to global in layout
// Z[b][x][zslot][ybin] (y natural-bin order, 16B lanes dense within 1 KiB).
// ---------------------------------------------------------------------------
__global__ __launch_bounds__(1024) void k_fft_zy(const float* __restrict__ ref,
                                                 const float* __restrict__ pred,
                                                 float2* __restrict__ Z, int b0) {
    __shared__ float sm[4 * 64 * 128];   // 131072 B
    float* p0re = sm;
    float* p0im = sm + 8192;
    float* p1re = sm + 16384;
    float* p1im = sm + 24576;
    const int t = threadIdx.x, l = t & 63, w = t >> 6;   // 16 waves
    const int x  = blockIdx.x & (N - 1);
    const int bl = blockIdx.x >> 7;
    float tc[7], ts[7];
    mk_tw(l, tc, ts);
    const int f2 = (int)(__brev((unsigned)l) >> 26) << 1;   // 2*bitrev6(l)
    const int sw = l & 31;

    const size_t inb = (size_t)(b0 + bl) * VOL + (size_t)x * NSQ;
#pragma unroll
    for (int k = 0; k < 8; ++k) {
        const int y = w * 8 + k;
        const float* rp = ref  + inb + (size_t)y * N;
        const float* pq = pred + inb + (size_t)y * N;
        float2 v0 = make_float2(rp[l],      pq[l]);        // C = ref + i*pred
        float2 v1 = make_float2(rp[l + 64], pq[l + 64]);
        fft128(v0, v1, tc, ts, l);
        const int a = l * 128 + (y ^ sw);   // lane l holds slots 2l, 2l+1
        p0re[a] = v0.x; p0im[a] = v0.y;
        p1re[a] = v1.x; p1im[a] = v1.y;
    }
    __syncthreads();
    const size_t zb = (size_t)bl * VOL + (size_t)x * NSQ;
#pragma unroll
    for (int k = 0; k < 8; ++k) {
        const int s = w * 8 + k;            // z-slot column (wave-uniform)
        const int j = s >> 1;
        const float* pr = (s & 1) ? p1re : p0re;
        const float* pi = (s & 1) ? p1im : p0im;
        const int base = j * 128 + (l ^ (j & 31));
        float2 v0 = make_float2(pr[base],      pi[base]);
        float2 v1 = make_float2(pr[base + 64], pi[base + 64]);
        fft128(v0, v1, tc, ts, l);
        *reinterpret_cast<float4*>(&Z[zb + (size_t)s * N + f2]) =
            make_float4(v0.x, v0.y, v1.x, v1.y);
    }
}

// ---------------------------------------------------------------------------
// Exact floor(sqrt(r2)) for integer r2.
// ---------------------------------------------------------------------------
__device__ inline int isqrt_i(int r2) {
    int s = (int)sqrtf((float)r2);
    s -= (s * s > r2);
    s += ((s + 1) * (s + 1) <= r2);
    return s;
}

// ---------------------------------------------------------------------------
// Pass 2 (fused x-FFT + Hermitian shell reduce).
// Block = (batch, z-slot, 16-wide ybin tile). Loads its tile and the mirror
// tile (-y, -z) for all x (128 B rows), x-FFTs columns in registers (LDS used
// only for the load transpose; odd pitch -> conflict-free), reduces straight
// from registers: the partner value conj-source C(-k) for lane l's bins sits
// at lanes p0 = bitrev6((64-bitrev6(l))&63) (reg v0) and p1 = 63-l (reg v1)
// of the mirror-column FFT -> 4 ds_bpermute, no write-back, no re-read.
// Full-space weight-1: each (y,z) line is primary for exactly one block.
// ---------------------------------------------------------------------------
__global__ __launch_bounds__(512) void k_fftx_reduce(const float2* __restrict__ Z,
                                                     float* __restrict__ accum, int b0) {
    const int t = threadIdx.x, l = t & 63, w = t >> 6;   // 8 waves
    const int yc = blockIdx.x & 7;
    const int zs = (blockIdx.x >> 3) & (N - 1);
    const int bl = blockIdx.x >> 10;

    const int fzb = binof(zs);
    const int fz  = fzb - ((fzb >= 64) ? N : 0);
    const int fzz = fz * fz;
    const int minfy = (yc < 4) ? yc * 16 : 113 - yc * 16;   // min |fy| over tile
    if (fzz + minfy * minfy >= NSHELL * NSHELL) return;     // whole tile >= shell 64

    __shared__ float reA[128 * TPX], imA[128 * TPX];
    __shared__ float reB[128 * TPX], imB[128 * TPX];        // 34816 B
    __shared__ float bins[4 * 193];

    const int mzs = binof((N - fzb) & (N - 1));             // slot of -fz (involution)
    const int y0  = yc * 16;
    const size_t zbase = (size_t)bl * VOL;
#pragma unroll
    for (int q = 0; q < 4; ++q) {
        const int e  = q * 512 + t;          // 2048 points per tile
        const int xx = e >> 4, yi = e & 15;
        const int y  = y0 + yi;
        const int my = (N - y) & (N - 1);
        const float2 av = Z[zbase + (size_t)xx * NSQ + (size_t)zs  * N + y];
        const float2 bv = Z[zbase + (size_t)xx * NSQ + (size_t)mzs * N + my];
        reA[xx * TPX + yi] = av.x; imA[xx * TPX + yi] = av.y;
        reB[xx * TPX + yi] = bv.x; imB[xx * TPX + yi] = bv.y;
    }
    for (int i = t; i < 4 * 193; i += 512) bins[i] = 0.f;

    float tc[7], ts[7];
    mk_tw(l, tc, ts);
    const int B6 = (int)(__brev((unsigned)l) >> 26);
    const int f2 = B6 << 1;
    const int p0 = (int)(__brev((unsigned)((64 - B6) & 63)) >> 26);
    const int p1 = 63 - l;
    const int fx0 = f2 - ((f2 >= 64) ? N : 0);
    const int fx0s = fx0 * fx0;
    const int fx1s = (fx0 + 1) * (fx0 + 1);
    __syncthreads();

    float* mybins = bins + (t & 3) * 193;
    float rC0 = 0.f, rP10 = 0.f, rP20 = 0.f; int cs0 = -1;
    float rC1 = 0.f, rP11 = 0.f, rP21 = 0.f; int cs1 = -1;
#define FLUSH(CS, C, P1V, P2V)                                                \
    if ((unsigned)(CS) < (unsigned)NSHELL) {                                  \
        atomicAdd(&mybins[(CS) * 3 + 0], (C));                                \
        atomicAdd(&mybins[(CS) * 3 + 1], (P1V));                              \
        atomicAdd(&mybins[(CS) * 3 + 2], (P2V));                              \
    }
#pragma unroll
    for (int k = 0; k < 2; ++k) {
        const int yi = w * 2 + k;            // consecutive fy per wave
        const int y  = y0 + yi;
        const int fy = y - ((y >= 64) ? N : 0);
        const int ryz = fy * fy + fzz;
        if (ryz >= NSHELL * NSHELL) continue;   // wave-uniform skip
        float2 a0 = make_float2(reA[l * TPX + yi],        imA[l * TPX + yi]);
        float2 a1 = make_float2(reA[(l + 64) * TPX + yi], imA[(l + 64) * TPX + yi]);
        fft128(a0, a1, tc, ts, l);
        float2 m0 = make_float2(reB[l * TPX + yi],        imB[l * TPX + yi]);
        float2 m1 = make_float2(reB[(l + 64) * TPX + yi], imB[(l + 64) * TPX + yi]);
        fft128(m0, m1, tc, ts, l);
        const float Bx0 = __shfl(m0.x, p0), By0 = __shfl(m0.y, p0);
        const float Bx1 = __shfl(m1.x, p1), By1 = __shfl(m1.y, p1);
        // bin0 = f2 (freq fx0)
        const int s0 = isqrt_i(fx0s + ryz);
        if (s0 != cs0) { FLUSH(cs0, rC0, rP10, rP20); cs0 = s0; rC0 = rP10 = rP20 = 0.f; }
        if (s0 < NSHELL) {
            const float F1x = 0.5f * (a0.x + Bx0);
            const float F1y = 0.5f * (a0.y - By0);
            const float F2x = 0.5f * (a0.y + By0);
            const float F2y = 0.5f * (Bx0 - a0.x);
            rC0  += F1x * F2x + F1y * F2y;
            rP10 += F1x * F1x + F1y * F1y;
            rP20 += F2x * F2x + F2y * F2y;
        }
        // bin1 = f2+1 (freq fx0+1)
        const int s1 = isqrt_i(fx1s + ryz);
        if (s1 != cs1) { FLUSH(cs1, rC1, rP11, rP21); cs1 = s1; rC1 = rP11 = rP21 = 0.f; }
        if (s1 < NSHELL) {
            const float F1x = 0.5f * (a1.x + Bx1);
            const float F1y = 0.5f * (a1.y - By1);
            const float F2x = 0.5f * (a1.y + By1);
            const float F2y = 0.5f * (Bx1 - a1.x);
            rC1  += F1x * F2x + F1y * F2y;
            rP11 += F1x * F1x + F1y * F1y;
            rP21 += F2x * F2x + F2y * F2y;
        }
    }
    FLUSH(cs0, rC0, rP10, rP20);
    FLUSH(cs1, rC1, rP11, rP21);
#undef FLUSH
    __syncthreads();

    const int smin = isqrt_i(fzz + minfy * minfy);   // lowest shell this block touches
    float* acc = accum + (size_t)(b0 + bl) * (NSHELL * 3);
    for (int i = smin * 3 + t; i < NSHELL * 3; i += 512) {
        const float v = bins[i] + bins[193 + i] + bins[2 * 193 + i] + bins[3 * 193 + i];
        atomicAdd(&acc[i], v);
    }
}

// ---------------------------------------------------------------------------
// Pass 3: FSC + loss. 512 threads = 8 batches x 64 shells.
// ---------------------------------------------------------------------------
__global__ __launch_bounds__(512) void k_final(const float* __restrict__ accum,
                                               float* __restrict__ out) {
    __shared__ float red[8];
    const int tid = threadIdx.x;
    const float* a = accum + (size_t)tid * 3;
    const float fsc = a[0] / (sqrtf(a[1] * a[2]) + 1e-8f);
    float v = fsc * fsc;
#pragma unroll
    for (int off = 32; off > 0; off >>= 1) v += __shfl_down(v, off);
    if ((tid & 63) == 0) red[tid >> 6] = v;
    __syncthreads();
    if (tid == 0) {
        float ssum = 0.f;
#pragma unroll
        for (int i = 0; i < 8; ++i) ssum += red[i];
        out[0] = 1.0f - ssum / 512.0f;
    }
}

extern "C" void kernel_launch(void* const* d_in, const int* in_sizes, int n_in,
                              void* d_out, int out_size, void* d_ws, size_t ws_size,
                              hipStream_t stream) {
    const float* ref  = (const float*)d_in[0];
    const float* pred = (const float*)d_in[1];
    float* out = (float*)d_out;

    char*   ws    = (char*)d_ws;
    float*  accum = (float*)ws;
    float2* Zbuf  = (float2*)(ws + 8192);

    const size_t zbytes = (size_t)VOL * sizeof(float2);
    int cap = 1;
    if (ws_size > 8192) {
        size_t c = (ws_size - 8192) / zbytes;
        cap = (c < 1) ? 1 : (c > BTOT ? BTOT : (int)c);
    }

    hipMemsetAsync(accum, 0, BTOT * NSHELL * 3 * sizeof(float), stream);

    for (int b0 = 0; b0 < BTOT; b0 += cap) {
        const int nb = (BTOT - b0 < cap) ? (BTOT - b0) : cap;
        k_fft_zy<<<nb * 128, 1024, 0, stream>>>(ref, pred, Zbuf, b0);
        k_fftx_reduce<<<nb * 1024, 512, 0, stream>>>(Zbuf, accum, b0);
    }
    k_final<<<1, 512, 0, stream>>>(accum, out);
}

// Round 3
// 337.818 us; speedup vs baseline: 1.2647x; 1.2647x over previous
//
#include <hip/hip_runtime.h>
#include <math.h>

#define N      128
#define NSQ    (N * N)          // 16384
#define VOL    (N * N * N)      // 2097152
#define NSHELL 64
#define BTOT   8
#define FPI    3.14159265358979323846f

#define TPX    17               // k2 tile pitch in floats (odd -> conflict-free column pulls)

// ---------------------------------------------------------------------------
// Per-lane twiddles for the wave-register 128-pt DIF FFT (verified r1/r2).
// ---------------------------------------------------------------------------
__device__ inline void mk_tw(int l, float* tc, float* ts) {
    __sincosf(-FPI * (float)l * (1.0f / 64.0f), &ts[0], &tc[0]);
#pragma unroll
    for (int k = 1; k <= 6; ++k) {
        const int h = 64 >> k;
        float s, c;
        __sincosf(-FPI * (float)(l & (h - 1)) / (float)h, &s, &c);
        const bool hi = (l & h) != 0;
        tc[k] = hi ? c : 1.0f;
        ts[k] = hi ? s : 0.0f;
    }
}

// ---------------------------------------------------------------------------
// 128-point DIF (Gentleman-Sande) FFT across one 64-lane wave.
// In:  lane l holds a[l] (v0), a[l+64] (v1), natural order.
// Out: lane l holds bins 2*bitrev6(l) (v0) and 2*bitrev6(l)+1 (v1).
// ---------------------------------------------------------------------------
__device__ inline void fft128(float2& v0, float2& v1,
                              const float* tc, const float* ts, int l) {
    {   // h = 64: in-lane, twiddle m = l
        const float dx = v0.x - v1.x, dy = v0.y - v1.y;
        v0.x += v1.x; v0.y += v1.y;
        v1.x = dx * tc[0] - dy * ts[0];
        v1.y = dx * ts[0] + dy * tc[0];
    }
#pragma unroll
    for (int k = 1; k <= 6; ++k) {
        const int h = 64 >> k;           // 32,16,8,4,2,1
        const float e = (l & h) ? -1.0f : 1.0f;
        const float c = tc[k], s = ts[k];
        const float o0x = __shfl_xor(v0.x, h), o0y = __shfl_xor(v0.y, h);
        const float o1x = __shfl_xor(v1.x, h), o1y = __shfl_xor(v1.y, h);
        const float t0x = fmaf(e, v0.x, o0x), t0y = fmaf(e, v0.y, o0y);
        const float t1x = fmaf(e, v1.x, o1x), t1y = fmaf(e, v1.y, o1y);
        v0.x = t0x * c - t0y * s;  v0.y = t0x * s + t0y * c;
        v1.x = t1x * c - t1y * s;  v1.y = t1x * s + t1y * c;
    }
}

// slot <-> bin permutation (involution): bin(slot s) = 2*bitrev6(s>>1) + (s&1)
__device__ inline int binof(int s) {
    return (int)(((__brev((unsigned)(s >> 1)) >> 26) << 1) | (unsigned)(s & 1));
}

// ---------------------------------------------------------------------------
// Pass 1 (fused z+y FFT): one block per (batch, x).
// LDS = 2 XOR-swizzled float2 planes P0/P1[64][128] = exactly 128 KiB.
// P(par) row j col c holds z-slot 2j+par, spatial y = c ^ (j&31):
//   phase-1 store (row = lane l, col uniform-xor): 2 lanes/bank-pair, free
//   phase-2 read  (row uniform, col = l^(j&31)):   2 lanes/bank-pair, free
// Structure: load-all(8 lines) -> fft-all -> store-all per phase, fully
// unrolled so 8 independent shfl chains overlap (ILP vs DS latency).
// ---------------------------------------------------------------------------
__global__ __launch_bounds__(1024) void k_fft_zy(const float* __restrict__ ref,
                                                 const float* __restrict__ pred,
                                                 float2* __restrict__ Z, int b0) {
    __shared__ float2 P0[64 * 128];   // 65536 B
    __shared__ float2 P1[64 * 128];   // 65536 B
    const int t = threadIdx.x, l = t & 63, w = t >> 6;   // 16 waves
    const int x  = blockIdx.x & (N - 1);
    const int bl = blockIdx.x >> 7;
    float tc[7], ts[7];
    mk_tw(l, tc, ts);
    const int f2 = (int)(__brev((unsigned)l) >> 26) << 1;   // 2*bitrev6(l)

    const size_t inb = (size_t)(b0 + bl) * VOL + (size_t)x * NSQ;
    const float* rp = ref  + inb;
    const float* pq = pred + inb;

    float2 V0[8], V1[8];
#pragma unroll
    for (int k = 0; k < 8; ++k) {                        // 32 loads in flight
        const int y = w * 8 + k;
        V0[k] = make_float2(rp[y * N + l],      pq[y * N + l]);
        V1[k] = make_float2(rp[y * N + l + 64], pq[y * N + l + 64]);
    }
#pragma unroll
    for (int k = 0; k < 8; ++k) fft128(V0[k], V1[k], tc, ts, l);
    const int row = l * 128, sw = l & 31;
#pragma unroll
    for (int k = 0; k < 8; ++k) {
        const int c = (w * 8 + k) ^ sw;                  // lane l holds slots 2l,2l+1
        P0[row + c] = V0[k];
        P1[row + c] = V1[k];
    }
    __syncthreads();

    float2 U0[8], U1[8];
#pragma unroll
    for (int k = 0; k < 8; ++k) {
        const int s = w * 8 + k, j = s >> 1;
        const float2* PP = (s & 1) ? P1 : P0;
        const int c = l ^ (j & 31);
        U0[k] = PP[j * 128 + c];
        U1[k] = PP[j * 128 + c + 64];
    }
#pragma unroll
    for (int k = 0; k < 8; ++k) fft128(U0[k], U1[k], tc, ts, l);
    const size_t zb = (size_t)bl * VOL + (size_t)x * NSQ;
#pragma unroll
    for (int k = 0; k < 8; ++k) {
        const int s = w * 8 + k;
        *reinterpret_cast<float4*>(&Z[zb + (size_t)s * N + f2]) =
            make_float4(U0[k].x, U0[k].y, U1[k].x, U1[k].y);
    }
}

// ---------------------------------------------------------------------------
// Exact floor(sqrt(r2)) for integer r2.
// ---------------------------------------------------------------------------
__device__ inline int isqrt_i(int r2) {
    int s = (int)sqrtf((float)r2);
    s -= (s * s > r2);
    s += ((s + 1) * (s + 1) <= r2);
    return s;
}

// ---------------------------------------------------------------------------
// Pass 2 (fused x-FFT + Hermitian shell reduce), half-space in kz.
// Contributions of k and -k are exactly equal in fp32 (F1(-k)=conj(F1(k)):
// |.|^2 and Re-cross identical), so only planes fz in [0,63] are enumerated
// (slots with (s&2)==0); each block still loads + FFTs the mirror tile
// (-y,-z) as the Hermitian data source, and its bins are flushed with
// weight 2 (fz=0: weight 1, plane self-pairs and is fully enumerated).
// FFT/load/reduce work is halved vs the full-space scheme.
// Per wave: 2 y-columns x (A,M) = 4 independent FFTs in flight.
// ---------------------------------------------------------------------------
__global__ __launch_bounds__(512) void k_fftx_reduce(const float2* __restrict__ Z,
                                                     float* __restrict__ accum, int b0) {
    const int t = threadIdx.x, l = t & 63, w = t >> 6;   // 8 waves
    const int yc = blockIdx.x & 7;
    const int q  = (blockIdx.x >> 3) & 63;
    const int bl = blockIdx.x >> 9;

    const int zs  = ((q >> 1) << 2) | (q & 1);   // slots whose bin is in [0,64)
    const int fz  = binof(zs);                   // fz in [0,63]
    const int fzz = fz * fz;
    const int minfy = (yc < 4) ? yc * 16 : 113 - yc * 16;   // min |fy| over tile
    if (fzz + minfy * minfy >= NSHELL * NSHELL) return;

    __shared__ float reA[128 * TPX], imA[128 * TPX];
    __shared__ float reB[128 * TPX], imB[128 * TPX];        // 34816 B
    __shared__ float bins[4 * 193];

    const int mzs = binof((N - fz) & (N - 1));   // slot holding bin -fz (fz=0 -> zs)
    const int y0  = yc * 16;
    const size_t zbase = (size_t)bl * VOL;
#pragma unroll
    for (int qq = 0; qq < 4; ++qq) {
        const int e  = qq * 512 + t;             // 2048 points per tile
        const int xx = e >> 4, yi = e & 15;
        const int y  = y0 + yi;
        const int my = (N - y) & (N - 1);
        const float2 av = Z[zbase + (size_t)xx * NSQ + (size_t)zs  * N + y];
        const float2 bv = Z[zbase + (size_t)xx * NSQ + (size_t)mzs * N + my];
        reA[xx * TPX + yi] = av.x; imA[xx * TPX + yi] = av.y;
        reB[xx * TPX + yi] = bv.x; imB[xx * TPX + yi] = bv.y;
    }
    for (int i = t; i < 4 * 193; i += 512) bins[i] = 0.f;

    float tc[7], ts[7];
    mk_tw(l, tc, ts);
    const int B6 = (int)(__brev((unsigned)l) >> 26);
    const int f2 = B6 << 1;
    const int p0 = (int)(__brev((unsigned)((64 - B6) & 63)) >> 26);
    const int p1 = 63 - l;
    const int fx0 = f2 - ((f2 >= 64) ? N : 0);
    const int fx0s = fx0 * fx0;
    const int fx1s = (fx0 + 1) * (fx0 + 1);
    __syncthreads();

    const int yv0 = y0 + w * 2;
    const int fy0 = yv0 - ((yv0 >= 64) ? N : 0);
    const int fy1 = (yv0 + 1) - (((yv0 + 1) >= 64) ? N : 0);
    const int r2yz[2] = { fy0 * fy0 + fzz, fy1 * fy1 + fzz };
    float* mybins = bins + (t & 3) * 193;

#define FLUSH(CS, C, P1V, P2V)                                                \
    if ((unsigned)(CS) < (unsigned)NSHELL) {                                  \
        atomicAdd(&mybins[(CS) * 3 + 0], (C));                                \
        atomicAdd(&mybins[(CS) * 3 + 1], (P1V));                              \
        atomicAdd(&mybins[(CS) * 3 + 2], (P2V));                              \
    }
    if (r2yz[0] < NSHELL * NSHELL || r2yz[1] < NSHELL * NSHELL) {
        float2 A0[2], A1[2], M0[2], M1[2];
#pragma unroll
        for (int k = 0; k < 2; ++k) {
            const int yi = w * 2 + k;
            A0[k] = make_float2(reA[l * TPX + yi],        imA[l * TPX + yi]);
            A1[k] = make_float2(reA[(l + 64) * TPX + yi], imA[(l + 64) * TPX + yi]);
            M0[k] = make_float2(reB[l * TPX + yi],        imB[l * TPX + yi]);
            M1[k] = make_float2(reB[(l + 64) * TPX + yi], imB[(l + 64) * TPX + yi]);
        }
#pragma unroll
        for (int k = 0; k < 2; ++k) {            // 4 independent shfl chains
            fft128(A0[k], A1[k], tc, ts, l);
            fft128(M0[k], M1[k], tc, ts, l);
        }
        float rC0 = 0.f, rP10 = 0.f, rP20 = 0.f; int cs0 = -1;
        float rC1 = 0.f, rP11 = 0.f, rP21 = 0.f; int cs1 = -1;
#pragma unroll
        for (int k = 0; k < 2; ++k) {
            const float Bx0 = __shfl(M0[k].x, p0), By0 = __shfl(M0[k].y, p0);
            const float Bx1 = __shfl(M1[k].x, p1), By1 = __shfl(M1[k].y, p1);
            // bin f2 (freq fx0)
            const int s0 = isqrt_i(fx0s + r2yz[k]);
            if (s0 != cs0) { FLUSH(cs0, rC0, rP10, rP20); cs0 = s0; rC0 = rP10 = rP20 = 0.f; }
            if (s0 < NSHELL) {
                const float F1x = 0.5f * (A0[k].x + Bx0);
                const float F1y = 0.5f * (A0[k].y - By0);
                const float F2x = 0.5f * (A0[k].y + By0);
                const float F2y = 0.5f * (Bx0 - A0[k].x);
                rC0  += F1x * F2x + F1y * F2y;
                rP10 += F1x * F1x + F1y * F1y;
                rP20 += F2x * F2x + F2y * F2y;
            }
            // bin f2+1 (freq fx0+1)
            const int s1 = isqrt_i(fx1s + r2yz[k]);
            if (s1 != cs1) { FLUSH(cs1, rC1, rP11, rP21); cs1 = s1; rC1 = rP11 = rP21 = 0.f; }
            if (s1 < NSHELL) {
                const float F1x = 0.5f * (A1[k].x + Bx1);
                const float F1y = 0.5f * (A1[k].y - By1);
                const float F2x = 0.5f * (A1[k].y + By1);
                const float F2y = 0.5f * (Bx1 - A1[k].x);
                rC1  += F1x * F2x + F1y * F2y;
                rP11 += F1x * F1x + F1y * F1y;
                rP21 += F2x * F2x + F2y * F2y;
            }
        }
        FLUSH(cs0, rC0, rP10, rP20);
        FLUSH(cs1, rC1, rP11, rP21);
    }
#undef FLUSH
    __syncthreads();

    const float wsc = (fz == 0) ? 1.f : 2.f;     // -fz plane contributes equally (exact)
    const int smin = isqrt_i(fzz + minfy * minfy);
    float* acc = accum + (size_t)(b0 + bl) * (NSHELL * 3);
    for (int i = smin * 3 + t; i < NSHELL * 3; i += 512) {
        const float v = bins[i] + bins[193 + i] + bins[2 * 193 + i] + bins[3 * 193 + i];
        atomicAdd(&acc[i], v * wsc);
    }
}

// ---------------------------------------------------------------------------
// Pass 3: FSC + loss. 512 threads = 8 batches x 64 shells.
// ---------------------------------------------------------------------------
__global__ __launch_bounds__(512) void k_final(const float* __restrict__ accum,
                                               float* __restrict__ out) {
    __shared__ float red[8];
    const int tid = threadIdx.x;
    const float* a = accum + (size_t)tid * 3;
    const float fsc = a[0] / (sqrtf(a[1] * a[2]) + 1e-8f);
    float v = fsc * fsc;
#pragma unroll
    for (int off = 32; off > 0; off >>= 1) v += __shfl_down(v, off);
    if ((tid & 63) == 0) red[tid >> 6] = v;
    __syncthreads();
    if (tid == 0) {
        float ssum = 0.f;
#pragma unroll
        for (int i = 0; i < 8; ++i) ssum += red[i];
        out[0] = 1.0f - ssum / 512.0f;
    }
}

extern "C" void kernel_launch(void* const* d_in, const int* in_sizes, int n_in,
                              void* d_out, int out_size, void* d_ws, size_t ws_size,
                              hipStream_t stream) {
    const float* ref  = (const float*)d_in[0];
    const float* pred = (const float*)d_in[1];
    float* out = (float*)d_out;

    char*   ws    = (char*)d_ws;
    float*  accum = (float*)ws;
    float2* Zbuf  = (float2*)(ws + 8192);

    const size_t zbytes = (size_t)VOL * sizeof(float2);
    int cap = 1;
    if (ws_size > 8192) {
        size_t c = (ws_size - 8192) / zbytes;
        cap = (c < 1) ? 1 : (c > BTOT ? BTOT : (int)c);
    }

    hipMemsetAsync(accum, 0, BTOT * NSHELL * 3 * sizeof(float), stream);

    for (int b0 = 0; b0 < BTOT; b0 += cap) {
        const int nb = (BTOT - b0 < cap) ? (BTOT - b0) : cap;
        k_fft_zy<<<nb * 128, 1024, 0, stream>>>(ref, pred, Zbuf, b0);
        k_fftx_reduce<<<nb * 512, 512, 0, stream>>>(Zbuf, accum, b0);
    }
    k_final<<<1, 512, 0, stream>>>(accum, out);
}

// Round 4
// 292.731 us; speedup vs baseline: 1.4595x; 1.1540x over previous
//
#include <hip/hip_runtime.h>
#include <math.h>

#define N      128
#define NSQ    (N * N)          // 16384
#define VOL    (N * N * N)      // 2097152
#define NSHELL 64
#define BTOT   8
#define FPI    3.14159265358979323846f

#define TPX    17               // k2 tile pitch in floats (odd -> conflict-free column pulls)

#if __has_builtin(__builtin_amdgcn_permlane32_swap) && __has_builtin(__builtin_amdgcn_permlane16_swap)
#define HAVE_PLSWAP 1
#else
#define HAVE_PLSWAP 0
#endif

typedef unsigned uint2v __attribute__((ext_vector_type(2)));

// ---------------------------------------------------------------------------
// Twiddles. c64/s64: exp(-i pi l/64) (in-lane stage). c32/s32, c16/s16: raw
// all-lane exp(-i pi (l&31)/32), exp(-i pi (l&15)/16) for the permlane-swap
// pair stages (role-adjusted in the no-permlane fallback). c8..e2, e1: role
// twiddles for the DPP/swizzle stages (hi lanes w=exp(-i pi (l&(h-1))/h),
// e=-1; lo lanes (1,0,+1)).
// ---------------------------------------------------------------------------
struct TW {
    float c64, s64;
    float c32, s32, c16, s16;
#if !HAVE_PLSWAP
    float e32, e16;
#endif
    float c8, s8, e8;
    float c4, s4, e4;
    float c2, s2, e2;
    float e1;
};

__device__ inline void mk_tw(int l, TW& w) {
    __sincosf(-FPI * (float)l * (1.0f / 64.0f), &w.s64, &w.c64);
#if HAVE_PLSWAP
    __sincosf(-FPI * (float)(l & 31) * (1.0f / 32.0f), &w.s32, &w.c32);
    __sincosf(-FPI * (float)(l & 15) * (1.0f / 16.0f), &w.s16, &w.c16);
#else
    { float s, c; __sincosf(-FPI * (float)(l & 31) * (1.0f / 32.0f), &s, &c);
      const bool hi = (l & 32); w.c32 = hi ? c : 1.f; w.s32 = hi ? s : 0.f; w.e32 = hi ? -1.f : 1.f; }
    { float s, c; __sincosf(-FPI * (float)(l & 15) * (1.0f / 16.0f), &s, &c);
      const bool hi = (l & 16); w.c16 = hi ? c : 1.f; w.s16 = hi ? s : 0.f; w.e16 = hi ? -1.f : 1.f; }
#endif
    { float s, c; __sincosf(-FPI * (float)(l & 7) * (1.0f / 8.0f), &s, &c);
      const bool hi = (l & 8); w.c8 = hi ? c : 1.f; w.s8 = hi ? s : 0.f; w.e8 = hi ? -1.f : 1.f; }
    { float s, c; __sincosf(-FPI * (float)(l & 3) * (1.0f / 4.0f), &s, &c);
      const bool hi = (l & 4); w.c4 = hi ? c : 1.f; w.s4 = hi ? s : 0.f; w.e4 = hi ? -1.f : 1.f; }
    { float s, c; __sincosf(-FPI * (float)(l & 1) * (1.0f / 2.0f), &s, &c);
      const bool hi = (l & 2); w.c2 = hi ? c : 1.f; w.s2 = hi ? s : 0.f; w.e2 = hi ? -1.f : 1.f; }
    w.e1 = (l & 1) ? -1.f : 1.f;
}

// ---------------------------------------------------------------------------
// Cross-lane primitives: DPP (VALU) for xor8/xor2/xor1, ds_swizzle for xor4,
// permlane{16,32}_swap (VALU) for the 16/32 pair stages.
// ---------------------------------------------------------------------------
template<int CTRL>
__device__ inline float2 xdpp(float2 v) {
    return make_float2(
        __int_as_float(__builtin_amdgcn_update_dpp(__float_as_int(v.x), __float_as_int(v.x), CTRL, 0xF, 0xF, false)),
        __int_as_float(__builtin_amdgcn_update_dpp(__float_as_int(v.y), __float_as_int(v.y), CTRL, 0xF, 0xF, false)));
}
__device__ inline float2 xswz4(float2 v) {   // xor4: BitMode (4<<10)|0x1F
    return make_float2(
        __int_as_float(__builtin_amdgcn_ds_swizzle(__float_as_int(v.x), 0x101F)),
        __int_as_float(__builtin_amdgcn_ds_swizzle(__float_as_int(v.y), 0x101F)));
}

// role butterfly: t = e*v + o ; out = t * (c + i s)   (lo: e=+1,c=1,s=0)
__device__ inline float2 bfly(float2 v, float2 o, float c, float s, float e) {
    const float tx = fmaf(e, v.x, o.x), ty = fmaf(e, v.y, o.y);
    return make_float2(tx * c - ty * s, tx * s + ty * c);
}

__device__ inline void bf64(float2& v0, float2& v1, float c, float s) {
    const float dx = v0.x - v1.x, dy = v0.y - v1.y;
    v0.x += v1.x; v0.y += v1.y;
    v1.x = dx * c - dy * s;
    v1.y = dx * s + dy * c;
}

#if HAVE_PLSWAP
__device__ inline void swp32f(float& a, float& b) {
    uint2v r = __builtin_amdgcn_permlane32_swap(__float_as_uint(a), __float_as_uint(b), false, false);
    a = __uint_as_float(r[0]); b = __uint_as_float(r[1]);
}
__device__ inline void swp16f(float& a, float& b) {
    uint2v r = __builtin_amdgcn_permlane16_swap(__float_as_uint(a), __float_as_uint(b), false, false);
    a = __uint_as_float(r[0]); b = __uint_as_float(r[1]);
}
// Pair butterfly at h=32/16 for two FFTs' same-position registers A,B.
// After swap: P/R hold lo elements, Q/S hold hi elements (slot-matched pairs
// of ONE fft per lane). sum/diff*w, swap back reassembles both FFTs exactly.
__device__ inline void pair32(float2& A, float2& B, float c, float s) {
    float P = A.x, Q = B.x, R = A.y, S = B.y;
    swp32f(P, Q); swp32f(R, S);
    const float sx = P + Q, sy = R + S;
    const float dx = P - Q, dy = R - S;
    float fx = dx * c - dy * s;
    float fy = dx * s + dy * c;
    float ax = sx, bx = fx, ay = sy, by = fy;
    swp32f(ax, bx); swp32f(ay, by);
    A = make_float2(ax, ay); B = make_float2(bx, by);
}
__device__ inline void pair16(float2& A, float2& B, float c, float s) {
    float P = A.x, Q = B.x, R = A.y, S = B.y;
    swp16f(P, Q); swp16f(R, S);
    const float sx = P + Q, sy = R + S;
    const float dx = P - Q, dy = R - S;
    float fx = dx * c - dy * s;
    float fy = dx * s + dy * c;
    float ax = sx, bx = fx, ay = sy, by = fy;
    swp16f(ax, bx); swp16f(ay, by);
    A = make_float2(ax, ay); B = make_float2(bx, by);
}
#else
__device__ inline float2 xshfl(float2 v, int m) {
    return make_float2(__shfl_xor(v.x, m), __shfl_xor(v.y, m));
}
#endif

// ---------------------------------------------------------------------------
// Two 128-point DIF FFTs (a, b) computed together across one 64-lane wave.
// In:  lane l holds elem l (v0) and l+64 (v1) of each FFT, natural order.
// Out: lane l holds bins 2*bitrev6(l) (v0) and 2*bitrev6(l)+1 (v1).
// Stages: h=64 in-lane; h=32/16 permlane-swap pair butterflies (VALU);
// h=8 DPP row_ror:8; h=4 ds_swizzle; h=2/1 DPP quad_perm. Arithmetic is
// bit-identical to the verified shfl_xor version.
// ---------------------------------------------------------------------------
__device__ inline void fft128p(float2& a0, float2& a1, float2& b0, float2& b1,
                               const TW& w) {
    bf64(a0, a1, w.c64, w.s64);
    bf64(b0, b1, w.c64, w.s64);
#if HAVE_PLSWAP
    pair32(a0, b0, w.c32, w.s32);
    pair32(a1, b1, w.c32, w.s32);
    pair16(a0, b0, w.c16, w.s16);
    pair16(a1, b1, w.c16, w.s16);
#else
    { float2 o = xshfl(a0, 32); a0 = bfly(a0, o, w.c32, w.s32, w.e32); }
    { float2 o = xshfl(a1, 32); a1 = bfly(a1, o, w.c32, w.s32, w.e32); }
    { float2 o = xshfl(b0, 32); b0 = bfly(b0, o, w.c32, w.s32, w.e32); }
    { float2 o = xshfl(b1, 32); b1 = bfly(b1, o, w.c32, w.s32, w.e32); }
    { float2 o = xshfl(a0, 16); a0 = bfly(a0, o, w.c16, w.s16, w.e16); }
    { float2 o = xshfl(a1, 16); a1 = bfly(a1, o, w.c16, w.s16, w.e16); }
    { float2 o = xshfl(b0, 16); b0 = bfly(b0, o, w.c16, w.s16, w.e16); }
    { float2 o = xshfl(b1, 16); b1 = bfly(b1, o, w.c16, w.s16, w.e16); }
#endif
    // h=8: DPP row_ror:8 == xor8
    { float2 o = xdpp<0x128>(a0); a0 = bfly(a0, o, w.c8, w.s8, w.e8); }
    { float2 o = xdpp<0x128>(a1); a1 = bfly(a1, o, w.c8, w.s8, w.e8); }
    { float2 o = xdpp<0x128>(b0); b0 = bfly(b0, o, w.c8, w.s8, w.e8); }
    { float2 o = xdpp<0x128>(b1); b1 = bfly(b1, o, w.c8, w.s8, w.e8); }
    // h=4: ds_swizzle xor4
    { float2 o = xswz4(a0); a0 = bfly(a0, o, w.c4, w.s4, w.e4); }
    { float2 o = xswz4(a1); a1 = bfly(a1, o, w.c4, w.s4, w.e4); }
    { float2 o = xswz4(b0); b0 = bfly(b0, o, w.c4, w.s4, w.e4); }
    { float2 o = xswz4(b1); b1 = bfly(b1, o, w.c4, w.s4, w.e4); }
    // h=2: quad_perm [2,3,0,1] == xor2
    { float2 o = xdpp<0x4E>(a0); a0 = bfly(a0, o, w.c2, w.s2, w.e2); }
    { float2 o = xdpp<0x4E>(a1); a1 = bfly(a1, o, w.c2, w.s2, w.e2); }
    { float2 o = xdpp<0x4E>(b0); b0 = bfly(b0, o, w.c2, w.s2, w.e2); }
    { float2 o = xdpp<0x4E>(b1); b1 = bfly(b1, o, w.c2, w.s2, w.e2); }
    // h=1: quad_perm [1,0,3,2] == xor1, twiddle == 1 (no rotation)
    { float2 o = xdpp<0xB1>(a0); a0.x = fmaf(w.e1, a0.x, o.x); a0.y = fmaf(w.e1, a0.y, o.y); }
    { float2 o = xdpp<0xB1>(a1); a1.x = fmaf(w.e1, a1.x, o.x); a1.y = fmaf(w.e1, a1.y, o.y); }
    { float2 o = xdpp<0xB1>(b0); b0.x = fmaf(w.e1, b0.x, o.x); b0.y = fmaf(w.e1, b0.y, o.y); }
    { float2 o = xdpp<0xB1>(b1); b1.x = fmaf(w.e1, b1.x, o.x); b1.y = fmaf(w.e1, b1.y, o.y); }
}

// slot <-> bin permutation (involution): bin(slot s) = 2*bitrev6(s>>1) + (s&1)
__device__ inline int binof(int s) {
    return (int)(((__brev((unsigned)(s >> 1)) >> 26) << 1) | (unsigned)(s & 1));
}

// ---------------------------------------------------------------------------
// Pass 1 (fused z+y FFT): one block per (batch, x).
// LDS = 2 XOR-swizzled float2 planes P0/P1[64][128] = 128 KiB (verified r3).
// ---------------------------------------------------------------------------
__global__ __launch_bounds__(1024) void k_fft_zy(const float* __restrict__ ref,
                                                 const float* __restrict__ pred,
                                                 float2* __restrict__ Z, int b0) {
    __shared__ float2 P0[64 * 128];   // 65536 B
    __shared__ float2 P1[64 * 128];   // 65536 B
    const int t = threadIdx.x, l = t & 63, w = t >> 6;   // 16 waves
    const int x  = blockIdx.x & (N - 1);
    const int bl = blockIdx.x >> 7;
    TW tw;
    mk_tw(l, tw);
    const int f2 = (int)(__brev((unsigned)l) >> 26) << 1;   // 2*bitrev6(l)

    const size_t inb = (size_t)(b0 + bl) * VOL + (size_t)x * NSQ;
    const float* rp = ref  + inb;
    const float* pq = pred + inb;

    float2 V0[8], V1[8];
#pragma unroll
    for (int k = 0; k < 8; ++k) {                        // 32 loads in flight
        const int y = w * 8 + k;
        V0[k] = make_float2(rp[y * N + l],      pq[y * N + l]);
        V1[k] = make_float2(rp[y * N + l + 64], pq[y * N + l + 64]);
    }
#pragma unroll
    for (int k = 0; k < 8; k += 2)
        fft128p(V0[k], V1[k], V0[k + 1], V1[k + 1], tw);
    const int row = l * 128, sw = l & 31;
#pragma unroll
    for (int k = 0; k < 8; ++k) {
        const int c = (w * 8 + k) ^ sw;                  // lane l holds slots 2l,2l+1
        P0[row + c] = V0[k];
        P1[row + c] = V1[k];
    }
    __syncthreads();

    float2 U0[8], U1[8];
#pragma unroll
    for (int k = 0; k < 8; ++k) {
        const int s = w * 8 + k, j = s >> 1;
        const float2* PP = (s & 1) ? P1 : P0;
        const int c = l ^ (j & 31);
        U0[k] = PP[j * 128 + c];
        U1[k] = PP[j * 128 + c + 64];
    }
#pragma unroll
    for (int k = 0; k < 8; k += 2)
        fft128p(U0[k], U1[k], U0[k + 1], U1[k + 1], tw);
    const size_t zb = (size_t)bl * VOL + (size_t)x * NSQ;
#pragma unroll
    for (int k = 0; k < 8; ++k) {
        const int s = w * 8 + k;
        *reinterpret_cast<float4*>(&Z[zb + (size_t)s * N + f2]) =
            make_float4(U0[k].x, U0[k].y, U1[k].x, U1[k].y);
    }
}

// ---------------------------------------------------------------------------
// Exact floor(sqrt(r2)) for integer r2.
// ---------------------------------------------------------------------------
__device__ inline int isqrt_i(int r2) {
    int s = (int)sqrtf((float)r2);
    s -= (s * s > r2);
    s += ((s + 1) * (s + 1) <= r2);
    return s;
}

// ---------------------------------------------------------------------------
// Pass 2 (fused x-FFT + Hermitian shell reduce), half-space in kz (verified
// r3: k/-k shell contributions are bitwise equal; weight 2, fz=0 weight 1).
// ---------------------------------------------------------------------------
__global__ __launch_bounds__(512) void k_fftx_reduce(const float2* __restrict__ Z,
                                                     float* __restrict__ accum, int b0) {
    const int t = threadIdx.x, l = t & 63, w = t >> 6;   // 8 waves
    const int yc = blockIdx.x & 7;
    const int q  = (blockIdx.x >> 3) & 63;
    const int bl = blockIdx.x >> 9;

    const int zs  = ((q >> 1) << 2) | (q & 1);   // slots whose bin is in [0,64)
    const int fz  = binof(zs);                   // fz in [0,63]
    const int fzz = fz * fz;
    const int minfy = (yc < 4) ? yc * 16 : 113 - yc * 16;   // min |fy| over tile
    if (fzz + minfy * minfy >= NSHELL * NSHELL) return;

    __shared__ float reA[128 * TPX], imA[128 * TPX];
    __shared__ float reB[128 * TPX], imB[128 * TPX];        // 34816 B
    __shared__ float bins[4 * 193];

    const int mzs = binof((N - fz) & (N - 1));   // slot holding bin -fz (fz=0 -> zs)
    const int y0  = yc * 16;
    const size_t zbase = (size_t)bl * VOL;
#pragma unroll
    for (int qq = 0; qq < 4; ++qq) {
        const int e  = qq * 512 + t;             // 2048 points per tile
        const int xx = e >> 4, yi = e & 15;
        const int y  = y0 + yi;
        const int my = (N - y) & (N - 1);
        const float2 av = Z[zbase + (size_t)xx * NSQ + (size_t)zs  * N + y];
        const float2 bv = Z[zbase + (size_t)xx * NSQ + (size_t)mzs * N + my];
        reA[xx * TPX + yi] = av.x; imA[xx * TPX + yi] = av.y;
        reB[xx * TPX + yi] = bv.x; imB[xx * TPX + yi] = bv.y;
    }
    for (int i = t; i < 4 * 193; i += 512) bins[i] = 0.f;

    TW tw;
    mk_tw(l, tw);
    const int B6 = (int)(__brev((unsigned)l) >> 26);
    const int f2 = B6 << 1;
    const int p0 = (int)(__brev((unsigned)((64 - B6) & 63)) >> 26);
    const int p1 = 63 - l;
    const int fx0 = f2 - ((f2 >= 64) ? N : 0);
    const int fx0s = fx0 * fx0;
    const int fx1s = (fx0 + 1) * (fx0 + 1);
    __syncthreads();

    const int yv0 = y0 + w * 2;
    const int fy0 = yv0 - ((yv0 >= 64) ? N : 0);
    const int fy1 = (yv0 + 1) - (((yv0 + 1) >= 64) ? N : 0);
    const int r2yz[2] = { fy0 * fy0 + fzz, fy1 * fy1 + fzz };
    float* mybins = bins + (t & 3) * 193;

#define FLUSH(CS, C, P1V, P2V)                                                \
    if ((unsigned)(CS) < (unsigned)NSHELL) {                                  \
        atomicAdd(&mybins[(CS) * 3 + 0], (C));                                \
        atomicAdd(&mybins[(CS) * 3 + 1], (P1V));                              \
        atomicAdd(&mybins[(CS) * 3 + 2], (P2V));                              \
    }
    if (r2yz[0] < NSHELL * NSHELL || r2yz[1] < NSHELL * NSHELL) {  // wave-uniform
        float2 A0[2], A1[2], M0[2], M1[2];
#pragma unroll
        for (int k = 0; k < 2; ++k) {
            const int yi = w * 2 + k;
            A0[k] = make_float2(reA[l * TPX + yi],        imA[l * TPX + yi]);
            A1[k] = make_float2(reA[(l + 64) * TPX + yi], imA[(l + 64) * TPX + yi]);
            M0[k] = make_float2(reB[l * TPX + yi],        imB[l * TPX + yi]);
            M1[k] = make_float2(reB[(l + 64) * TPX + yi], imB[(l + 64) * TPX + yi]);
        }
        fft128p(A0[0], A1[0], A0[1], A1[1], tw);
        fft128p(M0[0], M1[0], M0[1], M1[1], tw);
        float rC0 = 0.f, rP10 = 0.f, rP20 = 0.f; int cs0 = -1;
        float rC1 = 0.f, rP11 = 0.f, rP21 = 0.f; int cs1 = -1;
#pragma unroll
        for (int k = 0; k < 2; ++k) {
            const float Bx0 = __shfl(M0[k].x, p0), By0 = __shfl(M0[k].y, p0);
            const float Bx1 = __shfl(M1[k].x, p1), By1 = __shfl(M1[k].y, p1);
            // bin f2 (freq fx0)
            const int s0 = isqrt_i(fx0s + r2yz[k]);
            if (s0 != cs0) { FLUSH(cs0, rC0, rP10, rP20); cs0 = s0; rC0 = rP10 = rP20 = 0.f; }
            if (s0 < NSHELL) {
                const float F1x = 0.5f * (A0[k].x + Bx0);
                const float F1y = 0.5f * (A0[k].y - By0);
                const float F2x = 0.5f * (A0[k].y + By0);
                const float F2y = 0.5f * (Bx0 - A0[k].x);
                rC0  += F1x * F2x + F1y * F2y;
                rP10 += F1x * F1x + F1y * F1y;
                rP20 += F2x * F2x + F2y * F2y;
            }
            // bin f2+1 (freq fx0+1)
            const int s1 = isqrt_i(fx1s + r2yz[k]);
            if (s1 != cs1) { FLUSH(cs1, rC1, rP11, rP21); cs1 = s1; rC1 = rP11 = rP21 = 0.f; }
            if (s1 < NSHELL) {
                const float F1x = 0.5f * (A1[k].x + Bx1);
                const float F1y = 0.5f * (A1[k].y - By1);
                const float F2x = 0.5f * (A1[k].y + By1);
                const float F2y = 0.5f * (Bx1 - A1[k].x);
                rC1  += F1x * F2x + F1y * F2y;
                rP11 += F1x * F1x + F1y * F1y;
                rP21 += F2x * F2x + F2y * F2y;
            }
        }
        FLUSH(cs0, rC0, rP10, rP20);
        FLUSH(cs1, rC1, rP11, rP21);
    }
#undef FLUSH
    __syncthreads();

    const float wsc = (fz == 0) ? 1.f : 2.f;     // -fz plane contributes equally (exact)
    const int smin = isqrt_i(fzz + minfy * minfy);
    float* acc = accum + (size_t)(b0 + bl) * (NSHELL * 3);
    for (int i = smin * 3 + t; i < NSHELL * 3; i += 512) {
        const float v = bins[i] + bins[193 + i] + bins[2 * 193 + i] + bins[3 * 193 + i];
        atomicAdd(&acc[i], v * wsc);
    }
}

// ---------------------------------------------------------------------------
// Pass 3: FSC + loss. 512 threads = 8 batches x 64 shells.
// ---------------------------------------------------------------------------
__global__ __launch_bounds__(512) void k_final(const float* __restrict__ accum,
                                               float* __restrict__ out) {
    __shared__ float red[8];
    const int tid = threadIdx.x;
    const float* a = accum + (size_t)tid * 3;
    const float fsc = a[0] / (sqrtf(a[1] * a[2]) + 1e-8f);
    float v = fsc * fsc;
#pragma unroll
    for (int off = 32; off > 0; off >>= 1) v += __shfl_down(v, off);
    if ((tid & 63) == 0) red[tid >> 6] = v;
    __syncthreads();
    if (tid == 0) {
        float ssum = 0.f;
#pragma unroll
        for (int i = 0; i < 8; ++i) ssum += red[i];
        out[0] = 1.0f - ssum / 512.0f;
    }
}

extern "C" void kernel_launch(void* const* d_in, const int* in_sizes, int n_in,
                              void* d_out, int out_size, void* d_ws, size_t ws_size,
                              hipStream_t stream) {
    const float* ref  = (const float*)d_in[0];
    const float* pred = (const float*)d_in[1];
    float* out = (float*)d_out;

    char*   ws    = (char*)d_ws;
    float*  accum = (float*)ws;
    float2* Zbuf  = (float2*)(ws + 8192);

    const size_t zbytes = (size_t)VOL * sizeof(float2);
    int cap = 1;
    if (ws_size > 8192) {
        size_t c = (ws_size - 8192) / zbytes;
        cap = (c < 1) ? 1 : (c > BTOT ? BTOT : (int)c);
    }

    hipMemsetAsync(accum, 0, BTOT * NSHELL * 3 * sizeof(float), stream);

    for (int b0 = 0; b0 < BTOT; b0 += cap) {
        const int nb = (BTOT - b0 < cap) ? (BTOT - b0) : cap;
        k_fft_zy<<<nb * 128, 1024, 0, stream>>>(ref, pred, Zbuf, b0);
        k_fftx_reduce<<<nb * 512, 512, 0, stream>>>(Zbuf, accum, b0);
    }
    k_final<<<1, 512, 0, stream>>>(accum, out);
}

// Round 5
// 284.832 us; speedup vs baseline: 1.5000x; 1.0277x over previous
//
#include <hip/hip_runtime.h>
#include <math.h>

#define N      128
#define NSQ    (N * N)          // 16384
#define VOL    (N * N * N)      // 2097152
#define NSHELL 64
#define BTOT   8
#define FPI    3.14159265358979323846f

#define TP9    9                // k2 tile pitch in float2 (col stride 18 dwords -> 2/bank-pair, free)

#if __has_builtin(__builtin_amdgcn_permlane32_swap) && __has_builtin(__builtin_amdgcn_permlane16_swap)
#define HAVE_PLSWAP 1
#else
#define HAVE_PLSWAP 0
#endif

typedef unsigned uint2v __attribute__((ext_vector_type(2)));

// ---------------------------------------------------------------------------
// Twiddles. c64/s64: exp(-i pi l/64) (in-lane stage). c32/s32, c16/s16: raw
// all-lane exp(-i pi (l&31)/32), exp(-i pi (l&15)/16) for the permlane-swap
// pair stages (role-adjusted in the no-permlane fallback). c8..e2, e1: role
// twiddles for the DPP/swizzle stages (hi lanes w=exp(-i pi (l&(h-1))/h),
// e=-1; lo lanes (1,0,+1)).
// ---------------------------------------------------------------------------
struct TW {
    float c64, s64;
    float c32, s32, c16, s16;
#if !HAVE_PLSWAP
    float e32, e16;
#endif
    float c8, s8, e8;
    float c4, s4, e4;
    float c2, s2, e2;
    float e1;
};

__device__ inline void mk_tw(int l, TW& w) {
    __sincosf(-FPI * (float)l * (1.0f / 64.0f), &w.s64, &w.c64);
#if HAVE_PLSWAP
    __sincosf(-FPI * (float)(l & 31) * (1.0f / 32.0f), &w.s32, &w.c32);
    __sincosf(-FPI * (float)(l & 15) * (1.0f / 16.0f), &w.s16, &w.c16);
#else
    { float s, c; __sincosf(-FPI * (float)(l & 31) * (1.0f / 32.0f), &s, &c);
      const bool hi = (l & 32); w.c32 = hi ? c : 1.f; w.s32 = hi ? s : 0.f; w.e32 = hi ? -1.f : 1.f; }
    { float s, c; __sincosf(-FPI * (float)(l & 15) * (1.0f / 16.0f), &s, &c);
      const bool hi = (l & 16); w.c16 = hi ? c : 1.f; w.s16 = hi ? s : 0.f; w.e16 = hi ? -1.f : 1.f; }
#endif
    { float s, c; __sincosf(-FPI * (float)(l & 7) * (1.0f / 8.0f), &s, &c);
      const bool hi = (l & 8); w.c8 = hi ? c : 1.f; w.s8 = hi ? s : 0.f; w.e8 = hi ? -1.f : 1.f; }
    { float s, c; __sincosf(-FPI * (float)(l & 3) * (1.0f / 4.0f), &s, &c);
      const bool hi = (l & 4); w.c4 = hi ? c : 1.f; w.s4 = hi ? s : 0.f; w.e4 = hi ? -1.f : 1.f; }
    { float s, c; __sincosf(-FPI * (float)(l & 1) * (1.0f / 2.0f), &s, &c);
      const bool hi = (l & 2); w.c2 = hi ? c : 1.f; w.s2 = hi ? s : 0.f; w.e2 = hi ? -1.f : 1.f; }
    w.e1 = (l & 1) ? -1.f : 1.f;
}

// ---------------------------------------------------------------------------
// Cross-lane primitives: DPP (VALU) for xor8/xor2/xor1, ds_swizzle for xor4,
// permlane{16,32}_swap (VALU) for the 16/32 pair stages.
// ---------------------------------------------------------------------------
template<int CTRL>
__device__ inline float2 xdpp(float2 v) {
    return make_float2(
        __int_as_float(__builtin_amdgcn_update_dpp(__float_as_int(v.x), __float_as_int(v.x), CTRL, 0xF, 0xF, false)),
        __int_as_float(__builtin_amdgcn_update_dpp(__float_as_int(v.y), __float_as_int(v.y), CTRL, 0xF, 0xF, false)));
}
__device__ inline float2 xswz4(float2 v) {   // xor4: BitMode (4<<10)|0x1F
    return make_float2(
        __int_as_float(__builtin_amdgcn_ds_swizzle(__float_as_int(v.x), 0x101F)),
        __int_as_float(__builtin_amdgcn_ds_swizzle(__float_as_int(v.y), 0x101F)));
}

// role butterfly: t = e*v + o ; out = t * (c + i s)   (lo: e=+1,c=1,s=0)
__device__ inline float2 bfly(float2 v, float2 o, float c, float s, float e) {
    const float tx = fmaf(e, v.x, o.x), ty = fmaf(e, v.y, o.y);
    return make_float2(tx * c - ty * s, tx * s + ty * c);
}

__device__ inline void bf64(float2& v0, float2& v1, float c, float s) {
    const float dx = v0.x - v1.x, dy = v0.y - v1.y;
    v0.x += v1.x; v0.y += v1.y;
    v1.x = dx * c - dy * s;
    v1.y = dx * s + dy * c;
}

#if HAVE_PLSWAP
__device__ inline void swp32f(float& a, float& b) {
    uint2v r = __builtin_amdgcn_permlane32_swap(__float_as_uint(a), __float_as_uint(b), false, false);
    a = __uint_as_float(r[0]); b = __uint_as_float(r[1]);
}
__device__ inline void swp16f(float& a, float& b) {
    uint2v r = __builtin_amdgcn_permlane16_swap(__float_as_uint(a), __float_as_uint(b), false, false);
    a = __uint_as_float(r[0]); b = __uint_as_float(r[1]);
}
// Pair butterfly at h=32/16 for two FFTs' same-position registers A,B.
// After swap: P/R hold lo elements, Q/S hold hi elements (slot-matched pairs
// of ONE fft per lane). sum/diff*w, swap back reassembles both FFTs exactly.
__device__ inline void pair32(float2& A, float2& B, float c, float s) {
    float P = A.x, Q = B.x, R = A.y, S = B.y;
    swp32f(P, Q); swp32f(R, S);
    const float sx = P + Q, sy = R + S;
    const float dx = P - Q, dy = R - S;
    float fx = dx * c - dy * s;
    float fy = dx * s + dy * c;
    float ax = sx, bx = fx, ay = sy, by = fy;
    swp32f(ax, bx); swp32f(ay, by);
    A = make_float2(ax, ay); B = make_float2(bx, by);
}
__device__ inline void pair16(float2& A, float2& B, float c, float s) {
    float P = A.x, Q = B.x, R = A.y, S = B.y;
    swp16f(P, Q); swp16f(R, S);
    const float sx = P + Q, sy = R + S;
    const float dx = P - Q, dy = R - S;
    float fx = dx * c - dy * s;
    float fy = dx * s + dy * c;
    float ax = sx, bx = fx, ay = sy, by = fy;
    swp16f(ax, bx); swp16f(ay, by);
    A = make_float2(ax, ay); B = make_float2(bx, by);
}
#else
__device__ inline float2 xshfl(float2 v, int m) {
    return make_float2(__shfl_xor(v.x, m), __shfl_xor(v.y, m));
}
#endif

// ---------------------------------------------------------------------------
// Two 128-point DIF FFTs (a, b) computed together across one 64-lane wave.
// In:  lane l holds elem l (v0) and l+64 (v1) of each FFT, natural order.
// Out: lane l holds bins 2*bitrev6(l) (v0) and 2*bitrev6(l)+1 (v1).
// Stages: h=64 in-lane; h=32/16 permlane-swap pair butterflies (VALU);
// h=8 DPP row_ror:8; h=4 ds_swizzle; h=2/1 DPP quad_perm. (verified r4)
// ---------------------------------------------------------------------------
__device__ inline void fft128p(float2& a0, float2& a1, float2& b0, float2& b1,
                               const TW& w) {
    bf64(a0, a1, w.c64, w.s64);
    bf64(b0, b1, w.c64, w.s64);
#if HAVE_PLSWAP
    pair32(a0, b0, w.c32, w.s32);
    pair32(a1, b1, w.c32, w.s32);
    pair16(a0, b0, w.c16, w.s16);
    pair16(a1, b1, w.c16, w.s16);
#else
    { float2 o = xshfl(a0, 32); a0 = bfly(a0, o, w.c32, w.s32, w.e32); }
    { float2 o = xshfl(a1, 32); a1 = bfly(a1, o, w.c32, w.s32, w.e32); }
    { float2 o = xshfl(b0, 32); b0 = bfly(b0, o, w.c32, w.s32, w.e32); }
    { float2 o = xshfl(b1, 32); b1 = bfly(b1, o, w.c32, w.s32, w.e32); }
    { float2 o = xshfl(a0, 16); a0 = bfly(a0, o, w.c16, w.s16, w.e16); }
    { float2 o = xshfl(a1, 16); a1 = bfly(a1, o, w.c16, w.s16, w.e16); }
    { float2 o = xshfl(b0, 16); b0 = bfly(b0, o, w.c16, w.s16, w.e16); }
    { float2 o = xshfl(b1, 16); b1 = bfly(b1, o, w.c16, w.s16, w.e16); }
#endif
    // h=8: DPP row_ror:8 == xor8
    { float2 o = xdpp<0x128>(a0); a0 = bfly(a0, o, w.c8, w.s8, w.e8); }
    { float2 o = xdpp<0x128>(a1); a1 = bfly(a1, o, w.c8, w.s8, w.e8); }
    { float2 o = xdpp<0x128>(b0); b0 = bfly(b0, o, w.c8, w.s8, w.e8); }
    { float2 o = xdpp<0x128>(b1); b1 = bfly(b1, o, w.c8, w.s8, w.e8); }
    // h=4: ds_swizzle xor4
    { float2 o = xswz4(a0); a0 = bfly(a0, o, w.c4, w.s4, w.e4); }
    { float2 o = xswz4(a1); a1 = bfly(a1, o, w.c4, w.s4, w.e4); }
    { float2 o = xswz4(b0); b0 = bfly(b0, o, w.c4, w.s4, w.e4); }
    { float2 o = xswz4(b1); b1 = bfly(b1, o, w.c4, w.s4, w.e4); }
    // h=2: quad_perm [2,3,0,1] == xor2
    { float2 o = xdpp<0x4E>(a0); a0 = bfly(a0, o, w.c2, w.s2, w.e2); }
    { float2 o = xdpp<0x4E>(a1); a1 = bfly(a1, o, w.c2, w.s2, w.e2); }
    { float2 o = xdpp<0x4E>(b0); b0 = bfly(b0, o, w.c2, w.s2, w.e2); }
    { float2 o = xdpp<0x4E>(b1); b1 = bfly(b1, o, w.c2, w.s2, w.e2); }
    // h=1: quad_perm [1,0,3,2] == xor1, twiddle == 1
    { float2 o = xdpp<0xB1>(a0); a0.x = fmaf(w.e1, a0.x, o.x); a0.y = fmaf(w.e1, a0.y, o.y); }
    { float2 o = xdpp<0xB1>(a1); a1.x = fmaf(w.e1, a1.x, o.x); a1.y = fmaf(w.e1, a1.y, o.y); }
    { float2 o = xdpp<0xB1>(b0); b0.x = fmaf(w.e1, b0.x, o.x); b0.y = fmaf(w.e1, b0.y, o.y); }
    { float2 o = xdpp<0xB1>(b1); b1.x = fmaf(w.e1, b1.x, o.x); b1.y = fmaf(w.e1, b1.y, o.y); }
}

// slot <-> bin permutation (involution): bin(slot s) = 2*bitrev6(s>>1) + (s&1)
__device__ inline int binof(int s) {
    return (int)(((__brev((unsigned)(s >> 1)) >> 26) << 1) | (unsigned)(s & 1));
}

// ---------------------------------------------------------------------------
// Pass 1 (fused z+y FFT): one block per (batch, x).
// LDS = 2 XOR-swizzled float2 planes P0/P1[64][128] = 128 KiB (verified r3/r4).
// ---------------------------------------------------------------------------
__global__ __launch_bounds__(1024) void k_fft_zy(const float* __restrict__ ref,
                                                 const float* __restrict__ pred,
                                                 float2* __restrict__ Z, int b0) {
    __shared__ float2 P0[64 * 128];   // 65536 B
    __shared__ float2 P1[64 * 128];   // 65536 B
    const int t = threadIdx.x, l = t & 63, w = t >> 6;   // 16 waves
    const int x  = blockIdx.x & (N - 1);
    const int bl = blockIdx.x >> 7;
    TW tw;
    mk_tw(l, tw);
    const int f2 = (int)(__brev((unsigned)l) >> 26) << 1;   // 2*bitrev6(l)

    const size_t inb = (size_t)(b0 + bl) * VOL + (size_t)x * NSQ;
    const float* rp = ref  + inb;
    const float* pq = pred + inb;

    float2 V0[8], V1[8];
#pragma unroll
    for (int k = 0; k < 8; ++k) {                        // 32 loads in flight
        const int y = w * 8 + k;
        V0[k] = make_float2(rp[y * N + l],      pq[y * N + l]);
        V1[k] = make_float2(rp[y * N + l + 64], pq[y * N + l + 64]);
    }
#pragma unroll
    for (int k = 0; k < 8; k += 2)
        fft128p(V0[k], V1[k], V0[k + 1], V1[k + 1], tw);
    const int row = l * 128, sw = l & 31;
#pragma unroll
    for (int k = 0; k < 8; ++k) {
        const int c = (w * 8 + k) ^ sw;                  // lane l holds slots 2l,2l+1
        P0[row + c] = V0[k];
        P1[row + c] = V1[k];
    }
    __syncthreads();

    float2 U0[8], U1[8];
#pragma unroll
    for (int k = 0; k < 8; ++k) {
        const int s = w * 8 + k, j = s >> 1;
        const float2* PP = (s & 1) ? P1 : P0;
        const int c = l ^ (j & 31);
        U0[k] = PP[j * 128 + c];
        U1[k] = PP[j * 128 + c + 64];
    }
#pragma unroll
    for (int k = 0; k < 8; k += 2)
        fft128p(U0[k], U1[k], U0[k + 1], U1[k + 1], tw);
    const size_t zb = (size_t)bl * VOL + (size_t)x * NSQ;
#pragma unroll
    for (int k = 0; k < 8; ++k) {
        const int s = w * 8 + k;
        *reinterpret_cast<float4*>(&Z[zb + (size_t)s * N + f2]) =
            make_float4(U0[k].x, U0[k].y, U1[k].x, U1[k].y);
    }
}

// ---------------------------------------------------------------------------
// Exact floor(sqrt(r2)) for integer r2.
// ---------------------------------------------------------------------------
__device__ inline int isqrt_i(int r2) {
    int s = (int)sqrtf((float)r2);
    s -= (s * s > r2);
    s += ((s + 1) * (s + 1) <= r2);
    return s;
}

// ---------------------------------------------------------------------------
// Pass 2 (fused x-FFT + Hermitian shell reduce), half-space in kz (verified
// r3/r4: k/-k shell contributions are bitwise equal; weight 2, fz=0 weight 1).
// r5 restructure for latency: 256-thread / 4-wave blocks with 8-y tiles.
// LDS 21.5 KB -> 7 blocks/CU (28 waves, 87% occupancy ceiling): 7 independent
// load->barrier->FFT pipelines per CU interleave instead of 4 phase-locked
// 512-thread blocks. Loads stay 64 B-coalesced (8 y x 8 B per 8-lane group).
// Per wave: 2 y-columns; fft128p pairs (A,M) of the same y; partner
// extraction via p0/p1 shfl and run-length shell accumulation unchanged.
// ---------------------------------------------------------------------------
__global__ __launch_bounds__(256) void k_fftx_reduce(const float2* __restrict__ Z,
                                                     float* __restrict__ accum, int b0) {
    const int t = threadIdx.x, l = t & 63, w = t >> 6;   // 4 waves
    const int yc = blockIdx.x & 15;                      // 16 tiles of 8 y
    const int q  = (blockIdx.x >> 4) & 63;
    const int bl = blockIdx.x >> 10;

    const int zs  = ((q >> 1) << 2) | (q & 1);   // slots whose bin is in [0,64)
    const int fz  = binof(zs);                   // fz in [0,63]
    const int fzz = fz * fz;
    const int y0  = yc * 8;
    const int minfy = (yc < 8) ? y0 : 121 - y0;  // min |fy| over 8-y tile
    if (fzz + minfy * minfy >= NSHELL * NSHELL) return;

    __shared__ float2 TA[128 * TP9];             // 9216 B
    __shared__ float2 TB[128 * TP9];             // 9216 B
    __shared__ float bins[4 * 193];              // 3088 B

    const int mzs = binof((N - fz) & (N - 1));   // slot holding bin -fz (fz=0 -> zs)
    const size_t zbase = (size_t)bl * VOL;
#pragma unroll
    for (int qq = 0; qq < 4; ++qq) {
        const int e  = qq * 256 + t;             // 1024 points per tile
        const int xx = e >> 3, yi = e & 7;
        const int y  = y0 + yi;
        const int my = (N - y) & (N - 1);
        TA[xx * TP9 + yi] = Z[zbase + (size_t)xx * NSQ + (size_t)zs  * N + y];
        TB[xx * TP9 + yi] = Z[zbase + (size_t)xx * NSQ + (size_t)mzs * N + my];
    }
    for (int i = t; i < 4 * 193; i += 256) bins[i] = 0.f;

    TW tw;
    mk_tw(l, tw);
    const int B6 = (int)(__brev((unsigned)l) >> 26);
    const int f2 = B6 << 1;
    const int p0 = (int)(__brev((unsigned)((64 - B6) & 63)) >> 26);
    const int p1 = 63 - l;
    const int fx0 = f2 - ((f2 >= 64) ? N : 0);
    const int fx0s = fx0 * fx0;
    const int fx1s = (fx0 + 1) * (fx0 + 1);
    __syncthreads();

    const int yv0 = y0 + w * 2;                  // wave's 2 consecutive y's
    const int fy0 = yv0 - ((yv0 >= 64) ? N : 0);
    const int fy1 = (yv0 + 1) - (((yv0 + 1) >= 64) ? N : 0);
    const int r2yz[2] = { fy0 * fy0 + fzz, fy1 * fy1 + fzz };
    float* mybins = bins + (t & 3) * 193;

#define FLUSH(CS, C, P1V, P2V)                                                \
    if ((unsigned)(CS) < (unsigned)NSHELL) {                                  \
        atomicAdd(&mybins[(CS) * 3 + 0], (C));                                \
        atomicAdd(&mybins[(CS) * 3 + 1], (P1V));                              \
        atomicAdd(&mybins[(CS) * 3 + 2], (P2V));                              \
    }
    if (r2yz[0] < NSHELL * NSHELL || r2yz[1] < NSHELL * NSHELL) {  // wave-uniform
        float2 A0[2], A1[2], M0[2], M1[2];
#pragma unroll
        for (int k = 0; k < 2; ++k) {
            const int yi = w * 2 + k;
            A0[k] = TA[l * TP9 + yi];
            A1[k] = TA[(l + 64) * TP9 + yi];
            M0[k] = TB[l * TP9 + yi];
            M1[k] = TB[(l + 64) * TP9 + yi];
        }
        fft128p(A0[0], A1[0], M0[0], M1[0], tw);   // pair (A,M) of same y
        fft128p(A0[1], A1[1], M0[1], M1[1], tw);
        float rC0 = 0.f, rP10 = 0.f, rP20 = 0.f; int cs0 = -1;
        float rC1 = 0.f, rP11 = 0.f, rP21 = 0.f; int cs1 = -1;
#pragma unroll
        for (int k = 0; k < 2; ++k) {
            const float Bx0 = __shfl(M0[k].x, p0), By0 = __shfl(M0[k].y, p0);
            const float Bx1 = __shfl(M1[k].x, p1), By1 = __shfl(M1[k].y, p1);
            // bin f2 (freq fx0)
            const int s0 = isqrt_i(fx0s + r2yz[k]);
            if (s0 != cs0) { FLUSH(cs0, rC0, rP10, rP20); cs0 = s0; rC0 = rP10 = rP20 = 0.f; }
            if (s0 < NSHELL) {
                const float F1x = 0.5f * (A0[k].x + Bx0);
                const float F1y = 0.5f * (A0[k].y - By0);
                const float F2x = 0.5f * (A0[k].y + By0);
                const float F2y = 0.5f * (Bx0 - A0[k].x);
                rC0  += F1x * F2x + F1y * F2y;
                rP10 += F1x * F1x + F1y * F1y;
                rP20 += F2x * F2x + F2y * F2y;
            }
            // bin f2+1 (freq fx0+1)
            const int s1 = isqrt_i(fx1s + r2yz[k]);
            if (s1 != cs1) { FLUSH(cs1, rC1, rP11, rP21); cs1 = s1; rC1 = rP11 = rP21 = 0.f; }
            if (s1 < NSHELL) {
                const float F1x = 0.5f * (A1[k].x + Bx1);
                const float F1y = 0.5f * (A1[k].y - By1);
                const float F2x = 0.5f * (A1[k].y + By1);
                const float F2y = 0.5f * (Bx1 - A1[k].x);
                rC1  += F1x * F2x + F1y * F2y;
                rP11 += F1x * F1x + F1y * F1y;
                rP21 += F2x * F2x + F2y * F2y;
            }
        }
        FLUSH(cs0, rC0, rP10, rP20);
        FLUSH(cs1, rC1, rP11, rP21);
    }
#undef FLUSH
    __syncthreads();

    const float wsc = (fz == 0) ? 1.f : 2.f;     // -fz plane contributes equally (exact)
    const int smin = isqrt_i(fzz + minfy * minfy);
    float* acc = accum + (size_t)(b0 + bl) * (NSHELL * 3);
    for (int i = smin * 3 + t; i < NSHELL * 3; i += 256) {
        const float v = bins[i] + bins[193 + i] + bins[2 * 193 + i] + bins[3 * 193 + i];
        atomicAdd(&acc[i], v * wsc);
    }
}

// ---------------------------------------------------------------------------
// Pass 3: FSC + loss. 512 threads = 8 batches x 64 shells.
// ---------------------------------------------------------------------------
__global__ __launch_bounds__(512) void k_final(const float* __restrict__ accum,
                                               float* __restrict__ out) {
    __shared__ float red[8];
    const int tid = threadIdx.x;
    const float* a = accum + (size_t)tid * 3;
    const float fsc = a[0] / (sqrtf(a[1] * a[2]) + 1e-8f);
    float v = fsc * fsc;
#pragma unroll
    for (int off = 32; off > 0; off >>= 1) v += __shfl_down(v, off);
    if ((tid & 63) == 0) red[tid >> 6] = v;
    __syncthreads();
    if (tid == 0) {
        float ssum = 0.f;
#pragma unroll
        for (int i = 0; i < 8; ++i) ssum += red[i];
        out[0] = 1.0f - ssum / 512.0f;
    }
}

extern "C" void kernel_launch(void* const* d_in, const int* in_sizes, int n_in,
                              void* d_out, int out_size, void* d_ws, size_t ws_size,
                              hipStream_t stream) {
    const float* ref  = (const float*)d_in[0];
    const float* pred = (const float*)d_in[1];
    float* out = (float*)d_out;

    char*   ws    = (char*)d_ws;
    float*  accum = (float*)ws;
    float2* Zbuf  = (float2*)(ws + 8192);

    const size_t zbytes = (size_t)VOL * sizeof(float2);
    int cap = 1;
    if (ws_size > 8192) {
        size_t c = (ws_size - 8192) / zbytes;
        cap = (c < 1) ? 1 : (c > BTOT ? BTOT : (int)c);
    }

    hipMemsetAsync(accum, 0, BTOT * NSHELL * 3 * sizeof(float), stream);

    for (int b0 = 0; b0 < BTOT; b0 += cap) {
        const int nb = (BTOT - b0 < cap) ? (BTOT - b0) : cap;
        k_fft_zy<<<nb * 128, 1024, 0, stream>>>(ref, pred, Zbuf, b0);
        k_fftx_reduce<<<nb * 1024, 256, 0, stream>>>(Zbuf, accum, b0);
    }
    k_final<<<1, 512, 0, stream>>>(accum, out);
}